// Round 2
// baseline (62.328 us; speedup 1.0000x reference)
//
#include <hip/hip_runtime.h>

#define FLOOR_EPS 1e-6f

// Problem shape (from reference): B=32, C=1, F=128, T=8000
constexpr int Bq = 32, Cq = 1, Fq = 128, Tq = 8000;
constexpr int ROWS = Bq * Cq * Fq;   // 4096 independent rows
constexpr int LPT  = 32;             // elements per thread (one 128B cache line)
constexpr int NTH  = 256;            // threads per block
constexpr int ACTIVE = Tq / LPT;     // 250 active threads (250*32 == 8000)

__global__ __launch_bounds__(NTH)
void _PCEN_75033078661345_kernel(const float* __restrict__ x,
                                 const float* __restrict__ alpha,
                                 const float* __restrict__ delta,
                                 const float* __restrict__ root,
                                 const float* __restrict__ smooth,
                                 float* __restrict__ out,   // ROWS*T
                                 float* __restrict__ hid)   // ROWS
{
    const int r    = blockIdx.x;
    const int t    = threadIdx.x;
    const int lane = t & 63;
    const int wid  = t >> 6;

    const int c = (r / Fq) % Cq;
    const float w   = fminf(fmaxf(smooth[0], 0.f), 1.f);
    const float om  = 1.f - w;
    const float aa  = fminf(alpha[c], 1.f);
    const float dd  = delta[c];
    const float oor = 1.f / fmaxf(root[c], 1.f);

    const float* row = x + (size_t)r * Tq;

    // ---- Pass 1: load chunk into registers, local affine carry (A, cb) ----
    float xv[LPT];
    float Aa = 1.f, cb = 0.f;              // affine: y_out = Aa*y_in + cb
    if (t < ACTIVE) {
        const float4* p = (const float4*)(row + t * LPT);
        #pragma unroll
        for (int j = 0; j < LPT / 4; ++j) {
            float4 v = p[j];
            xv[4*j+0] = v.x; xv[4*j+1] = v.y; xv[4*j+2] = v.z; xv[4*j+3] = v.w;
        }
        float acc = 0.f;
        #pragma unroll
        for (int j = 0; j < LPT; ++j)
            acc = w * xv[j] + om * acc;
        cb = acc;
        // A = om^32 via repeated squaring (5 mults, deterministic)
        float om2 = om * om, om4 = om2 * om2, om8 = om4 * om4, om16 = om8 * om8;
        Aa = om16 * om16;
    }

    // ---- Wave-level inclusive scan of affine pairs (compose cur∘prev) ----
    float a = Aa, b = cb;
    #pragma unroll
    for (int d = 1; d < 64; d <<= 1) {
        float pa = __shfl_up(a, d);
        float pb = __shfl_up(b, d);
        if (lane >= d) { b = a * pb + b; a = a * pa; }
    }
    // exclusive within wave
    float lea = __shfl_up(a, 1);
    float leb = __shfl_up(b, 1);
    if (lane == 0) { lea = 1.f; leb = 0.f; }

    // ---- Cross-wave combine through LDS (4 waves) ----
    __shared__ float swa[NTH / 64], swb[NTH / 64];
    if (lane == 63) { swa[wid] = a; swb[wid] = b; }
    __syncthreads();
    float wpa = 1.f, wpb = 0.f;            // prefix of waves < wid
    for (int i = 0; i < wid; ++i) {
        float fa = swa[i], fb = swb[i];
        wpb = fa * wpb + fb;               // P_new = f_i ∘ P
        wpa = fa * wpa;
    }
    // total exclusive prefix E = lane_excl ∘ wave_excl
    const float Ea = lea * wpa;
    const float Eb = lea * wpb + leb;

    // ---- Pass 2: reconstruct ema, pointwise PCEN, write out ----
    const float x0 = row[0];               // scan init (ema[-1] = x[0])
    if (t < ACTIVE) {
        float acc = Ea * x0 + Eb;
        const bool  use_sqrt = (oor == 0.5f);
        const float droot = use_sqrt ? __builtin_amdgcn_sqrtf(dd)
                                     : __builtin_amdgcn_exp2f(oor * __builtin_amdgcn_logf(dd));
        float* orow = out + (size_t)r * Tq + t * LPT;
        #pragma unroll
        for (int j = 0; j < LPT / 4; ++j) {
            float4 o;
            float* op = &o.x;
            #pragma unroll
            for (int k = 0; k < 4; ++k) {
                float xx = xv[4*j + k];
                acc = w * xx + om * acc;                       // ema
                // (FLOOR + ema)^-a
                float dp = __builtin_amdgcn_exp2f(-aa * __builtin_amdgcn_logf(FLOOR_EPS + acc));
                float tt = xx * dp + dd;
                float oo = use_sqrt ? (__builtin_amdgcn_sqrtf(tt) - droot)
                                    : (__builtin_amdgcn_exp2f(oor * __builtin_amdgcn_logf(tt)) - droot);
                op[k] = oo;
            }
            ((float4*)orow)[j] = o;
        }
        if (t == ACTIVE - 1)
            hid[r] = acc;                  // final EMA -> hidden_state
    }
}

extern "C" void kernel_launch(void* const* d_in, const int* in_sizes, int n_in,
                              void* d_out, int out_size, void* d_ws, size_t ws_size,
                              hipStream_t stream) {
    const float* x      = (const float*)d_in[0];
    const float* alpha  = (const float*)d_in[1];
    const float* delta  = (const float*)d_in[2];
    const float* root   = (const float*)d_in[3];
    const float* smooth = (const float*)d_in[4];
    float* out = (float*)d_out;
    float* hid = out + (size_t)ROWS * Tq;

    _PCEN_75033078661345_kernel<<<ROWS, NTH, 0, stream>>>(
        x, alpha, delta, root, smooth, out, hid);
}